// Round 8
// baseline (17401.926 us; speedup 1.0000x reference)
//
#include <hip/hip_runtime.h>

typedef _Float16 f16;
typedef _Float16 half8 __attribute__((ext_vector_type(8)));
typedef float f32x4 __attribute__((ext_vector_type(4)));
typedef int i32x4 __attribute__((ext_vector_type(4)));

#define SEQ 512
#define NB 128
#define NH 768
#define NFEAT 128
#define NGRP 4
#define BG 32
#define NCOL 48
#define NWG (NGRP*NCOL)
#define KW8 96
#define FSTR 20          /* fin row stride in f32: +80 f32 per m-group => +16 banks */

// workspace layout
#define OFF_WIH   0LL
#define OFF_WHH   3538944LL
#define OFF_WLIN  7077888LL
#define OFF_XBUF  7274496LL
#define OFF_HBUF  7471104LL
#define OFF_CTR   7667712LL   /* 4 groups * 512 steps * 4B = 8 KB (16 KB reserved) */
#define OFF_Y     7684096LL
#define OFF_TN    108347392LL
#define WS_NEED   (OFF_TN + 1024)

__global__ void fill_sentinel(float* out, long long n) {
  long long i = (long long)blockIdx.x * blockDim.x + threadIdx.x;
  long long stride = (long long)gridDim.x * blockDim.x;
  for (; i < n; i += stride) out[i] = -2.0f;
}

__global__ void prep_kernel(const float* __restrict__ Ho, const float* __restrict__ Hn,
                            const unsigned int* __restrict__ Traw,
                            const float* __restrict__ Wih, const float* __restrict__ Whh,
                            const float* __restrict__ Wlin,
                            f16* __restrict__ wih16, f16* __restrict__ whh16,
                            f16* __restrict__ wlin16,
                            f16* __restrict__ xbuf, f16* __restrict__ hbuf,
                            int* __restrict__ Tn)
{
  long long idx = (long long)blockIdx.x * blockDim.x + threadIdx.x;
  long long stride = (long long)gridDim.x * blockDim.x;
  for (long long i = idx; i < 2304LL * 768LL; i += stride) {
    wih16[i] = (f16)Wih[i];
    whh16[i] = (f16)Whh[i];
  }
  for (long long i = idx; i < 128LL * 768LL; i += stride) {
    long long b = i / 768, h = i % 768;
    wlin16[i] = (f16)Wlin[i];
    xbuf[i] = (f16)Ho[(b * 32 + 31) * 768 + h];   // H_o[:, -1, :]
    hbuf[i] = (f16)Hn[i];                          // H_n[0]
  }
  // Normalize T: detect int64 (all odd 32-bit words zero) vs int32.
  if (blockIdx.x == 0 && threadIdx.x < 128) {
    bool allz = true;
    for (int i = 0; i < 64; ++i) allz = allz && (Traw[2 * i + 1] == 0u);
    int t = threadIdx.x;
    Tn[t] = allz ? (int)Traw[2 * t] : (int)Traw[t];
  }
}

__global__ void __launch_bounds__(512, 1)
gru_kernel(const f16* __restrict__ wih16, const f16* __restrict__ whh16,
           const f16* __restrict__ xbuf, const f16* __restrict__ hbuf,
           const float* __restrict__ Hn,
           const float* __restrict__ b_ih, const float* __restrict__ b_hh,
           f16* __restrict__ Y, unsigned int* __restrict__ ctr)
{
  const int wg  = blockIdx.x;
  const int g   = wg & (NGRP - 1);   // batch group 0..3
  const int c   = wg >> 2;           // column slice 0..47
  const int tid = threadIdx.x;
  const int lane = tid & 63;
  const int wv  = tid >> 6;          // wave 0..7 (K-split)
  const int j0  = c * 16;
  const int ks  = wv * KW8;
  const int bbase = g * BG;

  // weights: [wv][gate6][kt3] blocks of 64 lanes x 16B = 147456 B
  __shared__ __align__(16) f16 wlds[8 * 6 * 3 * 512];
  // shared gate accumulator: [gate6][b 32 x stride FSTR] f32 = 15360 B  (total 162816)
  __shared__ float fin[6 * BG * FSTR];

  const int n15 = lane & 15;
  const int kg8 = (lane >> 4) * 8;

  // gate-phase assignment: one (batch, col) per thread; h carried in fp32 register
  const int gb = tid >> 4;           // 0..31 batch within group
  const int gj = tid & 15;
  const int jglob = j0 + gj;
  float hcarry = Hn[(size_t)(bbase + gb) * NH + jglob];
  const float bi_r = b_ih[jglob], bi_z = b_ih[768 + jglob], bi_n = b_ih[1536 + jglob];
  const float bh_r = b_hh[jglob], bh_z = b_hh[768 + jglob], bh_n = b_hh[1536 + jglob];

  // ---- one-time: stage this WG's weight slice into LDS (identity per-lane roundtrip)
#pragma unroll
  for (int gt = 0; gt < 6; ++gt) {
    const f16* Wsrc = (gt < 3) ? wih16 : whh16;
    const f16* base = Wsrc + (size_t)((gt % 3) * 768 + j0 + n15) * NH + ks + kg8;
#pragma unroll
    for (int kt = 0; kt < 3; ++kt) {
      i32x4 v = *(const i32x4*)(base + kt * 32);
      *(i32x4*)(wlds + ((wv * 6 + gt) * 3 + kt) * 512 + lane * 8) = v;
    }
  }
  // ---- one-time: init fin with biases (thread owns 6 slots)
  {
    const int fo = gb * FSTR + gj;
    fin[0 * BG * FSTR + fo] = bi_r;
    fin[1 * BG * FSTR + fo] = bi_z;
    fin[2 * BG * FSTR + fo] = bi_n;
    fin[3 * BG * FSTR + fo] = bh_r;
    fin[4 * BG * FSTR + fo] = bh_z;
    fin[5 * BG * FSTR + fo] = bh_n;
  }
  __syncthreads();

  const size_t arow0 = (size_t)(bbase + n15) * NH + ks + kg8;
  const size_t arow1 = arow0 + (size_t)16 * NH;
  const size_t ywr   = (size_t)(bbase + gb) * NH + jglob;
  const int mrow = (lane >> 4) * 4;
  const int fo_g = gb * FSTR + gj;

  unsigned int* cbase = ctr + ((size_t)g << 9);

  for (int s = 0; s < SEQ; ++s) {
    // ---- wait for all 48 column-WGs of this group to finish step s-1 ----
    if (s > 0 && tid == 0) {
      unsigned int* cp = cbase + (s - 1);
      while (__hip_atomic_load(cp, __ATOMIC_RELAXED, __HIP_MEMORY_SCOPE_AGENT) < NCOL)
        __builtin_amdgcn_s_sleep(1);
    }
    __syncthreads();   // C: release; h(s-1) visible at LLC

    const f16* hsrc = (s == 0) ? hbuf : (Y + (size_t)(s - 1) * (NB * NH));
    const f16* xsrc = (s == 0) ? xbuf : hsrc;

    half8 Af0_0 = *(const half8*)(xsrc + arow0);
    half8 Af0_1 = *(const half8*)(xsrc + arow0 + 32);
    half8 Af0_2 = *(const half8*)(xsrc + arow0 + 64);
    half8 Af1_0 = *(const half8*)(xsrc + arow1);
    half8 Af1_1 = *(const half8*)(xsrc + arow1 + 32);
    half8 Af1_2 = *(const half8*)(xsrc + arow1 + 64);

    f32x4 acc[2][6];
#pragma unroll
    for (int bt = 0; bt < 2; ++bt)
#pragma unroll
      for (int gt = 0; gt < 6; ++gt) acc[bt][gt] = (f32x4){0.f, 0.f, 0.f, 0.f};

    const f16* wbase = wlds + (wv * 6) * 3 * 512 + lane * 8;

    // ih gates (use x)
#pragma unroll
    for (int gt = 0; gt < 3; ++gt) {
      half8 B0 = *(const half8*)(wbase + (gt * 3 + 0) * 512);
      half8 B1 = *(const half8*)(wbase + (gt * 3 + 1) * 512);
      half8 B2 = *(const half8*)(wbase + (gt * 3 + 2) * 512);
      acc[0][gt] = __builtin_amdgcn_mfma_f32_16x16x32_f16(Af0_0, B0, acc[0][gt], 0, 0, 0);
      acc[1][gt] = __builtin_amdgcn_mfma_f32_16x16x32_f16(Af1_0, B0, acc[1][gt], 0, 0, 0);
      acc[0][gt] = __builtin_amdgcn_mfma_f32_16x16x32_f16(Af0_1, B1, acc[0][gt], 0, 0, 0);
      acc[1][gt] = __builtin_amdgcn_mfma_f32_16x16x32_f16(Af1_1, B1, acc[1][gt], 0, 0, 0);
      acc[0][gt] = __builtin_amdgcn_mfma_f32_16x16x32_f16(Af0_2, B2, acc[0][gt], 0, 0, 0);
      acc[1][gt] = __builtin_amdgcn_mfma_f32_16x16x32_f16(Af1_2, B2, acc[1][gt], 0, 0, 0);
    }

    if (s == 0) {   // hh gates use h0, not x0
      Af0_0 = *(const half8*)(hbuf + arow0);
      Af0_1 = *(const half8*)(hbuf + arow0 + 32);
      Af0_2 = *(const half8*)(hbuf + arow0 + 64);
      Af1_0 = *(const half8*)(hbuf + arow1);
      Af1_1 = *(const half8*)(hbuf + arow1 + 32);
      Af1_2 = *(const half8*)(hbuf + arow1 + 64);
    }

    // hh gates (use h)
#pragma unroll
    for (int gt = 3; gt < 6; ++gt) {
      half8 B0 = *(const half8*)(wbase + (gt * 3 + 0) * 512);
      half8 B1 = *(const half8*)(wbase + (gt * 3 + 1) * 512);
      half8 B2 = *(const half8*)(wbase + (gt * 3 + 2) * 512);
      acc[0][gt] = __builtin_amdgcn_mfma_f32_16x16x32_f16(Af0_0, B0, acc[0][gt], 0, 0, 0);
      acc[1][gt] = __builtin_amdgcn_mfma_f32_16x16x32_f16(Af1_0, B0, acc[1][gt], 0, 0, 0);
      acc[0][gt] = __builtin_amdgcn_mfma_f32_16x16x32_f16(Af0_1, B1, acc[0][gt], 0, 0, 0);
      acc[1][gt] = __builtin_amdgcn_mfma_f32_16x16x32_f16(Af1_1, B1, acc[1][gt], 0, 0, 0);
      acc[0][gt] = __builtin_amdgcn_mfma_f32_16x16x32_f16(Af0_2, B2, acc[0][gt], 0, 0, 0);
      acc[1][gt] = __builtin_amdgcn_mfma_f32_16x16x32_f16(Af1_2, B2, acc[1][gt], 0, 0, 0);
    }

    // ---- reduce across waves: ds_add_f32 into fin (2-way bank pattern = free) ----
    // value (m = bt*16 + mrow + r, n = n15) of gate gt -> fin[gt][m][n15]
#pragma unroll
    for (int bt = 0; bt < 2; ++bt)
#pragma unroll
      for (int gt = 0; gt < 6; ++gt)
#pragma unroll
        for (int r = 0; r < 4; ++r)
          atomicAdd(&fin[gt * (BG * FSTR) + (bt * 16 + mrow + r) * FSTR + n15],
                    acc[bt][gt][r]);

    __syncthreads();   // A: all adds done

    // gate phase: read own 6 sums (bias included), re-init for next step
    float gir = fin[0 * BG * FSTR + fo_g];
    float giz = fin[1 * BG * FSTR + fo_g];
    float gin = fin[2 * BG * FSTR + fo_g];
    float ghr = fin[3 * BG * FSTR + fo_g];
    float ghz = fin[4 * BG * FSTR + fo_g];
    float ghn = fin[5 * BG * FSTR + fo_g];
    fin[0 * BG * FSTR + fo_g] = bi_r;
    fin[1 * BG * FSTR + fo_g] = bi_z;
    fin[2 * BG * FSTR + fo_g] = bi_n;
    fin[3 * BG * FSTR + fo_g] = bh_r;
    fin[4 * BG * FSTR + fo_g] = bh_z;
    fin[5 * BG * FSTR + fo_g] = bh_n;

    float rr = 1.f / (1.f + __expf(-(gir + ghr)));
    float zz = 1.f / (1.f + __expf(-(giz + ghz)));
    float xn = gin + rr * ghn;
    float nn = 1.f - 2.f / (__expf(2.f * xn) + 1.f);
    float hnew = (1.f - zz) * nn + zz * hcarry;
    hcarry = hnew;

    // pack pair (gj even|odd) into dword, agent-scope relaxed store -> LLC (sc1)
    unsigned int u = (unsigned int)__builtin_bit_cast(unsigned short, (f16)hnew);
    unsigned int partner = (unsigned int)__shfl_xor((int)u, 1);
    if ((tid & 1) == 0) {
      unsigned int val = u | (partner << 16);
      unsigned int* dst = (unsigned int*)(Y + (size_t)s * (NB * NH) + ywr);
      __hip_atomic_store(dst, val, __ATOMIC_RELAXED, __HIP_MEMORY_SCOPE_AGENT);
    }

    // B: each wave drains its vmcnt before s_barrier => all Y stores at LLC
    __syncthreads();
    if (tid == 0)
      __hip_atomic_fetch_add(cbase + s, 1u, __ATOMIC_RELAXED, __HIP_MEMORY_SCOPE_AGENT);
  }
}

__global__ void __launch_bounds__(256)
proj_kernel(const f16* __restrict__ Y, const f16* __restrict__ wlin16,
            const float* __restrict__ b_lin, const int* __restrict__ Tn,
            float* __restrict__ out)
{
  // rows r = s*128 + b over Y viewed as [512*128][768]; each WG does 64 rows x 128 cols
  const int tid = threadIdx.x;
  const int lane = tid & 63;
  const int wv = tid >> 6;
  const int r0 = blockIdx.x * 64 + wv * 16;
  const int n15 = lane & 15;
  const int kg8 = (lane >> 4) * 8;
  const size_t arow_off = (size_t)(r0 + n15) * NH + kg8;

  f32x4 acc[8];
#pragma unroll
  for (int nf = 0; nf < 8; ++nf) acc[nf] = (f32x4){0.f, 0.f, 0.f, 0.f};

  for (int kt = 0; kt < 24; ++kt) {
    half8 a = *(const half8*)(Y + arow_off + kt * 32);
#pragma unroll
    for (int nf = 0; nf < 8; ++nf) {
      half8 bfr = *(const half8*)(wlin16 + (size_t)(nf * 16 + n15) * NH + kt * 32 + kg8);
      acc[nf] = __builtin_amdgcn_mfma_f32_16x16x32_f16(a, bfr, acc[nf], 0, 0, 0);
    }
  }

#pragma unroll
  for (int nf = 0; nf < 8; ++nf) {
    int fcol = nf * 16 + n15;
    float bl = b_lin[fcol];
#pragma unroll
    for (int r = 0; r < 4; ++r) {
      int row = r0 + (lane >> 4) * 4 + r;
      int s = row >> 7, b = row & 127;
      int t = 511 - s;
      float v = (t < Tn[b]) ? (acc[nf][r] + bl) : -1.0f;
      out[((size_t)b * 512 + t) * NFEAT + fcol] = v;
    }
  }
}

extern "C" void kernel_launch(void* const* d_in, const int* in_sizes, int n_in,
                              void* d_out, int out_size, void* d_ws, size_t ws_size,
                              hipStream_t stream) {
  const float* Ho   = (const float*)d_in[0];
  const float* Hn   = (const float*)d_in[1];
  const unsigned int* Traw = (const unsigned int*)d_in[2];
  const float* Wih  = (const float*)d_in[3];
  const float* Whh  = (const float*)d_in[4];
  const float* bih  = (const float*)d_in[5];
  const float* bhh  = (const float*)d_in[6];
  const float* Wlin = (const float*)d_in[7];
  const float* blin = (const float*)d_in[8];
  float* out = (float*)d_out;

  if (ws_size < (size_t)WS_NEED) {
    fill_sentinel<<<1024, 256, 0, stream>>>(out, (long long)out_size);
    return;
  }

  char* ws = (char*)d_ws;
  f16* wih16  = (f16*)(ws + OFF_WIH);
  f16* whh16  = (f16*)(ws + OFF_WHH);
  f16* wlin16 = (f16*)(ws + OFF_WLIN);
  f16* xbuf   = (f16*)(ws + OFF_XBUF);
  f16* hbuf   = (f16*)(ws + OFF_HBUF);
  unsigned int* ctr = (unsigned int*)(ws + OFF_CTR);
  f16* Y      = (f16*)(ws + OFF_Y);
  int* Tn     = (int*)(ws + OFF_TN);

  hipMemsetAsync(ctr, 0, NGRP * SEQ * sizeof(unsigned int), stream);
  prep_kernel<<<512, 256, 0, stream>>>(Ho, Hn, Traw, Wih, Whh, Wlin,
                                       wih16, whh16, wlin16, xbuf, hbuf, Tn);
  gru_kernel<<<NWG, 512, 0, stream>>>(wih16, whh16, xbuf, hbuf, Hn, bih, bhh, Y, ctr);
  proj_kernel<<<1024, 256, 0, stream>>>(Y, wlin16, blin, Tn, out);
}

// Round 9
// 2111.269 us; speedup vs baseline: 8.2424x; 8.2424x over previous
//
#include <hip/hip_runtime.h>

typedef _Float16 f16;
typedef _Float16 half8 __attribute__((ext_vector_type(8)));
typedef float f32x4 __attribute__((ext_vector_type(4)));
typedef int i32x4 __attribute__((ext_vector_type(4)));

#define SEQ 512
#define NB 128
#define NH 768
#define NFEAT 128
#define NGRP 4
#define BG 32
#define NCOL 48
#define NWG (NGRP*NCOL)
#define KW 192          /* K per wave (4-wave K-split) */
#define NKT 6
#define NRES 27         /* weight blocks per wave resident in LDS (of 36) */

// workspace layout
#define OFF_WIH   0LL
#define OFF_WHH   3538944LL
#define OFF_WLIN  7077888LL
#define OFF_XBUF  7274496LL
#define OFF_HBUF  7471104LL
#define OFF_CTR   7667712LL   /* 4 groups * 512 steps * 4B = 8 KB (16 KB reserved) */
#define OFF_Y     7684096LL
#define OFF_TN    108347392LL
#define WS_NEED   (OFF_TN + 1024)

__global__ void fill_sentinel(float* out, long long n) {
  long long i = (long long)blockIdx.x * blockDim.x + threadIdx.x;
  long long stride = (long long)gridDim.x * blockDim.x;
  for (; i < n; i += stride) out[i] = -2.0f;
}

__global__ void prep_kernel(const float* __restrict__ Ho, const float* __restrict__ Hn,
                            const unsigned int* __restrict__ Traw,
                            const float* __restrict__ Wih, const float* __restrict__ Whh,
                            const float* __restrict__ Wlin,
                            f16* __restrict__ wih16, f16* __restrict__ whh16,
                            f16* __restrict__ wlin16,
                            f16* __restrict__ xbuf, f16* __restrict__ hbuf,
                            int* __restrict__ Tn)
{
  long long idx = (long long)blockIdx.x * blockDim.x + threadIdx.x;
  long long stride = (long long)gridDim.x * blockDim.x;
  for (long long i = idx; i < 2304LL * 768LL; i += stride) {
    wih16[i] = (f16)Wih[i];
    whh16[i] = (f16)Whh[i];
  }
  for (long long i = idx; i < 128LL * 768LL; i += stride) {
    long long b = i / 768, h = i % 768;
    wlin16[i] = (f16)Wlin[i];
    xbuf[i] = (f16)Ho[(b * 32 + 31) * 768 + h];   // H_o[:, -1, :]
    hbuf[i] = (f16)Hn[i];                          // H_n[0]
  }
  // Normalize T: detect int64 (all odd 32-bit words zero) vs int32.
  if (blockIdx.x == 0 && threadIdx.x < 128) {
    bool allz = true;
    for (int i = 0; i < 64; ++i) allz = allz && (Traw[2 * i + 1] == 0u);
    int t = threadIdx.x;
    Tn[t] = allz ? (int)Traw[2 * t] : (int)Traw[t];
  }
}

__global__ void __launch_bounds__(256, 1)
gru_kernel(const f16* __restrict__ wih16, const f16* __restrict__ whh16,
           const f16* __restrict__ xbuf, const f16* __restrict__ hbuf,
           const float* __restrict__ Hn,
           const float* __restrict__ b_ih, const float* __restrict__ b_hh,
           f16* __restrict__ Y, unsigned int* __restrict__ ctr)
{
  const int wg  = blockIdx.x;
  const int g   = wg & (NGRP - 1);   // batch group 0..3
  const int c   = wg >> 2;           // column slice 0..47
  const int tid = threadIdx.x;
  const int lane = tid & 63;
  const int wv  = tid >> 6;          // wave 0..3 (K-split, KW=192)
  const int j0  = c * 16;
  const int ks  = wv * KW;
  const int bbase = g * BG;

  // resident weights: [wv][block<27][64 lanes * 16B] = 110592 B
  __shared__ __align__(16) f16 wbuf[4 * NRES * 512];
  // partial exchange: [wv][frag(bt*6+gt)][lane] f32x4 = 49152 B   (total 159744)
  __shared__ f32x4 pb[4 * 12 * 64];

  const int n15 = lane & 15;
  const int kg8 = (lane >> 4) * 8;

  // ---- one-time: stage blocks 0..26 (gt*6+kt) of this wave's K-slice into LDS ----
#pragma unroll
  for (int gt = 0; gt < 6; ++gt) {
    const f16* Wsrc = (gt < 3) ? wih16 : whh16;
    const f16* base = Wsrc + (size_t)((gt % 3) * 768 + j0 + n15) * NH + ks + kg8;
#pragma unroll
    for (int kt = 0; kt < NKT; ++kt) {
      int idx = gt * 6 + kt;
      if (idx < NRES)
        *(i32x4*)(wbuf + (wv * NRES + idx) * 512 + lane * 8) =
            *(const i32x4*)(base + kt * 32);
    }
  }

  // gate phase: thread handles pairs (m=gb, n=gj) and (m=gb+16, n=gj)
  const int gb = tid >> 4;           // 0..15
  const int gj = tid & 15;
  const int jglob = j0 + gj;
  float hc0 = Hn[(size_t)(bbase + gb) * NH + jglob];
  float hc1 = Hn[(size_t)(bbase + 16 + gb) * NH + jglob];
  const float bi_r = b_ih[jglob], bi_z = b_ih[768 + jglob], bi_n = b_ih[1536 + jglob];
  const float bh_r = b_hh[jglob], bh_z = b_hh[768 + jglob], bh_n = b_hh[1536 + jglob];

  const size_t arow0 = (size_t)(bbase + n15) * NH + ks + kg8;
  const size_t arow1 = arow0 + (size_t)16 * NH;
  const size_t ywr0  = (size_t)(bbase + gb) * NH + jglob;
  const size_t ywr1  = ywr0 + (size_t)16 * NH;

  // reader offset within a frag: l = (gb>>2)*16 + gj, r = gb&3
  const int l4r = (((gb >> 2) * 16 + gj) << 2) + (gb & 3);

  // inline (non-resident) weight addresses: blocks 27..35 = g4k3..5, g5k0..5
  const f16* b4 = whh16 + (size_t)(1 * 768 + j0 + n15) * NH + ks + kg8;
  const f16* b5 = whh16 + (size_t)(2 * 768 + j0 + n15) * NH + ks + kg8;

  unsigned int* cbase = ctr + ((size_t)g << 9);

  __syncthreads();   // staging visible

  for (int s = 0; s < SEQ; ++s) {
    const f16* hsrc = (s == 0) ? hbuf : (Y + (size_t)(s - 1) * (NB * NH));
    const f16* xsrc = (s == 0) ? xbuf : hsrc;

    half8 A0[NKT], A1[NKT];
#pragma unroll
    for (int kt = 0; kt < NKT; ++kt) {
      A0[kt] = *(const half8*)(xsrc + arow0 + kt * 32);
      A1[kt] = *(const half8*)(xsrc + arow1 + kt * 32);
    }
    // inline weights for gt4 (kt 3..5) and gt5 (kt 0..5)
    half8 I43 = *(const half8*)(b4 + 3 * 32);
    half8 I44 = *(const half8*)(b4 + 4 * 32);
    half8 I45 = *(const half8*)(b4 + 5 * 32);
    half8 I50 = *(const half8*)(b5 + 0 * 32);
    half8 I51 = *(const half8*)(b5 + 1 * 32);
    half8 I52 = *(const half8*)(b5 + 2 * 32);
    half8 I53 = *(const half8*)(b5 + 3 * 32);
    half8 I54 = *(const half8*)(b5 + 4 * 32);
    half8 I55 = *(const half8*)(b5 + 5 * 32);

    f32x4 acc0[6], acc1[6];
#pragma unroll
    for (int gt = 0; gt < 6; ++gt) {
      acc0[gt] = (f32x4){0.f, 0.f, 0.f, 0.f};
      acc1[gt] = (f32x4){0.f, 0.f, 0.f, 0.f};
    }

    const f16* wb = wbuf + (size_t)(wv * NRES) * 512 + lane * 8;

    // ih gates 0..2 (x input) — all resident
#pragma unroll
    for (int gt = 0; gt < 3; ++gt) {
#pragma unroll
      for (int kt = 0; kt < NKT; ++kt) {
        half8 B = *(const half8*)(wb + (gt * 6 + kt) * 512);
        acc0[gt] = __builtin_amdgcn_mfma_f32_16x16x32_f16(A0[kt], B, acc0[gt], 0, 0, 0);
        acc1[gt] = __builtin_amdgcn_mfma_f32_16x16x32_f16(A1[kt], B, acc1[gt], 0, 0, 0);
      }
    }

    if (s == 0) {   // hh gates use h0, not x0
#pragma unroll
      for (int kt = 0; kt < NKT; ++kt) {
        A0[kt] = *(const half8*)(hbuf + arow0 + kt * 32);
        A1[kt] = *(const half8*)(hbuf + arow1 + kt * 32);
      }
    }

    // hh gate 3 (r) — resident (blocks 18..23)
#pragma unroll
    for (int kt = 0; kt < NKT; ++kt) {
      half8 B = *(const half8*)(wb + (18 + kt) * 512);
      acc0[3] = __builtin_amdgcn_mfma_f32_16x16x32_f16(A0[kt], B, acc0[3], 0, 0, 0);
      acc1[3] = __builtin_amdgcn_mfma_f32_16x16x32_f16(A1[kt], B, acc1[3], 0, 0, 0);
    }
    // hh gate 4 (z) — kt 0..2 resident (24..26), kt 3..5 inline
#pragma unroll
    for (int kt = 0; kt < 3; ++kt) {
      half8 B = *(const half8*)(wb + (24 + kt) * 512);
      acc0[4] = __builtin_amdgcn_mfma_f32_16x16x32_f16(A0[kt], B, acc0[4], 0, 0, 0);
      acc1[4] = __builtin_amdgcn_mfma_f32_16x16x32_f16(A1[kt], B, acc1[4], 0, 0, 0);
    }
    acc0[4] = __builtin_amdgcn_mfma_f32_16x16x32_f16(A0[3], I43, acc0[4], 0, 0, 0);
    acc1[4] = __builtin_amdgcn_mfma_f32_16x16x32_f16(A1[3], I43, acc1[4], 0, 0, 0);
    acc0[4] = __builtin_amdgcn_mfma_f32_16x16x32_f16(A0[4], I44, acc0[4], 0, 0, 0);
    acc1[4] = __builtin_amdgcn_mfma_f32_16x16x32_f16(A1[4], I44, acc1[4], 0, 0, 0);
    acc0[4] = __builtin_amdgcn_mfma_f32_16x16x32_f16(A0[5], I45, acc0[4], 0, 0, 0);
    acc1[4] = __builtin_amdgcn_mfma_f32_16x16x32_f16(A1[5], I45, acc1[4], 0, 0, 0);
    // hh gate 5 (n) — fully inline
    acc0[5] = __builtin_amdgcn_mfma_f32_16x16x32_f16(A0[0], I50, acc0[5], 0, 0, 0);
    acc1[5] = __builtin_amdgcn_mfma_f32_16x16x32_f16(A1[0], I50, acc1[5], 0, 0, 0);
    acc0[5] = __builtin_amdgcn_mfma_f32_16x16x32_f16(A0[1], I51, acc0[5], 0, 0, 0);
    acc1[5] = __builtin_amdgcn_mfma_f32_16x16x32_f16(A1[1], I51, acc1[5], 0, 0, 0);
    acc0[5] = __builtin_amdgcn_mfma_f32_16x16x32_f16(A0[2], I52, acc0[5], 0, 0, 0);
    acc1[5] = __builtin_amdgcn_mfma_f32_16x16x32_f16(A1[2], I52, acc1[5], 0, 0, 0);
    acc0[5] = __builtin_amdgcn_mfma_f32_16x16x32_f16(A0[3], I53, acc0[5], 0, 0, 0);
    acc1[5] = __builtin_amdgcn_mfma_f32_16x16x32_f16(A1[3], I53, acc1[5], 0, 0, 0);
    acc0[5] = __builtin_amdgcn_mfma_f32_16x16x32_f16(A0[4], I54, acc0[5], 0, 0, 0);
    acc1[5] = __builtin_amdgcn_mfma_f32_16x16x32_f16(A1[4], I54, acc1[5], 0, 0, 0);
    acc0[5] = __builtin_amdgcn_mfma_f32_16x16x32_f16(A0[5], I55, acc0[5], 0, 0, 0);
    acc1[5] = __builtin_amdgcn_mfma_f32_16x16x32_f16(A1[5], I55, acc1[5], 0, 0, 0);

    // partials -> LDS: 12 ds_write_b128 per thread
#pragma unroll
    for (int gt = 0; gt < 6; ++gt) {
      pb[wv * 768 + gt * 64 + lane]        = acc0[gt];
      pb[wv * 768 + (6 + gt) * 64 + lane]  = acc1[gt];
    }
    __syncthreads();   // A: partials visible

    // gate phase: 2 (m,n) pairs per thread, reduce 4 wave-partials each
    const float* pf = (const float*)pb;
#pragma unroll
    for (int p = 0; p < 2; ++p) {
      float gir = bi_r, giz = bi_z, gin = bi_n, ghr = bh_r, ghz = bh_z, ghn = bh_n;
#pragma unroll
      for (int ww = 0; ww < 4; ++ww) {
        const float* q = pf + ww * 3072 + p * 1536 + l4r;
        gir += q[0];    giz += q[256];  gin += q[512];
        ghr += q[768];  ghz += q[1024]; ghn += q[1280];
      }
      float hcarry = p ? hc1 : hc0;
      float rr = 1.f / (1.f + __expf(-(gir + ghr)));
      float zz = 1.f / (1.f + __expf(-(giz + ghz)));
      float xn = gin + rr * ghn;
      float nn = 1.f - 2.f / (__expf(2.f * xn) + 1.f);
      float hnew = (1.f - zz) * nn + zz * hcarry;
      if (p) hc1 = hnew; else hc0 = hnew;

      unsigned int u = (unsigned int)__builtin_bit_cast(unsigned short, (f16)hnew);
      unsigned int partner = (unsigned int)__shfl_xor((int)u, 1);
      if ((tid & 1) == 0) {
        unsigned int val = u | (partner << 16);
        size_t off = p ? ywr1 : ywr0;
        unsigned int* dst = (unsigned int*)(Y + (size_t)s * (NB * NH) + off);
        __hip_atomic_store(dst, val, __ATOMIC_RELAXED, __HIP_MEMORY_SCOPE_AGENT);
      }
    }

    // B: drain (all Y stores of this WG at LLC), then count + poll + release
    __syncthreads();
    if (tid == 0) {
      unsigned int* cp = cbase + s;
      __hip_atomic_fetch_add(cp, 1u, __ATOMIC_RELAXED, __HIP_MEMORY_SCOPE_AGENT);
      while (__hip_atomic_load(cp, __ATOMIC_RELAXED, __HIP_MEMORY_SCOPE_AGENT) < NCOL)
        __builtin_amdgcn_s_sleep(1);
    }
    __syncthreads();   // C: release
  }
}

__global__ void __launch_bounds__(256)
proj_kernel(const f16* __restrict__ Y, const f16* __restrict__ wlin16,
            const float* __restrict__ b_lin, const int* __restrict__ Tn,
            float* __restrict__ out)
{
  // rows r = s*128 + b over Y viewed as [512*128][768]; each WG does 64 rows x 128 cols
  const int tid = threadIdx.x;
  const int lane = tid & 63;
  const int wv = tid >> 6;
  const int r0 = blockIdx.x * 64 + wv * 16;
  const int n15 = lane & 15;
  const int kg8 = (lane >> 4) * 8;
  const size_t arow_off = (size_t)(r0 + n15) * NH + kg8;

  f32x4 acc[8];
#pragma unroll
  for (int nf = 0; nf < 8; ++nf) acc[nf] = (f32x4){0.f, 0.f, 0.f, 0.f};

  for (int kt = 0; kt < 24; ++kt) {
    half8 a = *(const half8*)(Y + arow_off + kt * 32);
#pragma unroll
    for (int nf = 0; nf < 8; ++nf) {
      half8 bfr = *(const half8*)(wlin16 + (size_t)(nf * 16 + n15) * NH + kt * 32 + kg8);
      acc[nf] = __builtin_amdgcn_mfma_f32_16x16x32_f16(a, bfr, acc[nf], 0, 0, 0);
    }
  }

#pragma unroll
  for (int nf = 0; nf < 8; ++nf) {
    int fcol = nf * 16 + n15;
    float bl = b_lin[fcol];
#pragma unroll
    for (int r = 0; r < 4; ++r) {
      int row = r0 + (lane >> 4) * 4 + r;
      int s = row >> 7, b = row & 127;
      int t = 511 - s;
      float v = (t < Tn[b]) ? (acc[nf][r] + bl) : -1.0f;
      out[((size_t)b * 512 + t) * NFEAT + fcol] = v;
    }
  }
}

extern "C" void kernel_launch(void* const* d_in, const int* in_sizes, int n_in,
                              void* d_out, int out_size, void* d_ws, size_t ws_size,
                              hipStream_t stream) {
  const float* Ho   = (const float*)d_in[0];
  const float* Hn   = (const float*)d_in[1];
  const unsigned int* Traw = (const unsigned int*)d_in[2];
  const float* Wih  = (const float*)d_in[3];
  const float* Whh  = (const float*)d_in[4];
  const float* bih  = (const float*)d_in[5];
  const float* bhh  = (const float*)d_in[6];
  const float* Wlin = (const float*)d_in[7];
  const float* blin = (const float*)d_in[8];
  float* out = (float*)d_out;

  if (ws_size < (size_t)WS_NEED) {
    fill_sentinel<<<1024, 256, 0, stream>>>(out, (long long)out_size);
    return;
  }

  char* ws = (char*)d_ws;
  f16* wih16  = (f16*)(ws + OFF_WIH);
  f16* whh16  = (f16*)(ws + OFF_WHH);
  f16* wlin16 = (f16*)(ws + OFF_WLIN);
  f16* xbuf   = (f16*)(ws + OFF_XBUF);
  f16* hbuf   = (f16*)(ws + OFF_HBUF);
  unsigned int* ctr = (unsigned int*)(ws + OFF_CTR);
  f16* Y      = (f16*)(ws + OFF_Y);
  int* Tn     = (int*)(ws + OFF_TN);

  hipMemsetAsync(ctr, 0, NGRP * SEQ * sizeof(unsigned int), stream);
  prep_kernel<<<512, 256, 0, stream>>>(Ho, Hn, Traw, Wih, Whh, Wlin,
                                       wih16, whh16, wlin16, xbuf, hbuf, Tn);
  gru_kernel<<<NWG, 256, 0, stream>>>(wih16, whh16, xbuf, hbuf, Hn, bih, bhh, Y, ctr);
  proj_kernel<<<1024, 256, 0, stream>>>(Y, wlin16, blin, Tn, out);
}